// Round 1
// baseline (5619.923 us; speedup 1.0000x reference)
//
#include <hip/hip_runtime.h>
#include <hip/hip_bf16.h>

#define DEVI __device__ __forceinline__

typedef float f32x4 __attribute__((ext_vector_type(4)));
typedef __bf16 bfx8 __attribute__((ext_vector_type(8)));

constexpr int NODES = 20000;
constexpr int FIN = 256;
constexpr int HH = 512;

DEVI ushort f2b(float f) {
  uint x = __float_as_uint(f);
  return (ushort)((x + 0x7fffu + ((x >> 16) & 1u)) >> 16);
}

DEVI void async16(const void* g, void* l) {
  __builtin_amdgcn_global_load_lds(
      (const __attribute__((address_space(1))) void*)g,
      (__attribute__((address_space(3))) void*)l, 16, 0, 0);
}

// ---------------- weight transpose: W[K,N] f32 -> Wt[N,K] bf16 ----------------
__global__ void wtrans(const float* __restrict__ W, ushort* __restrict__ Wt,
                       int K, int N) {
  const int idx = blockIdx.x * 256 + threadIdx.x;
  if (idx >= K * N) return;
  const int n = idx / K;
  const int k = idx - n * K;
  Wt[idx] = f2b(W[(size_t)k * N + n]);
}

// ---------------- scatter-add, f32 input, F=256 ----------------
__global__ void scatter_f32(const float* __restrict__ x, const int* __restrict__ ei,
                            float* __restrict__ agg, int E) {
  const int gw = (int)((blockIdx.x * 256 + threadIdx.x) >> 6);
  const int lane = threadIdx.x & 63;
  if (gw >= E) return;
  const int src = ei[gw];
  const int dst = ei[E + gw];
  const float4 v = *(const float4*)(x + (size_t)src * FIN + lane * 4);
  float* o = agg + (size_t)dst * FIN + lane * 4;
  atomicAdd(o + 0, v.x);
  atomicAdd(o + 1, v.y);
  atomicAdd(o + 2, v.z);
  atomicAdd(o + 3, v.w);
}

// ---------------- scatter-add, bf16 input, F=512 ----------------
__global__ void scatter_bf16(const ushort* __restrict__ h, const int* __restrict__ ei,
                             float* __restrict__ agg, int E) {
  const int gw = (int)((blockIdx.x * 256 + threadIdx.x) >> 6);
  const int lane = threadIdx.x & 63;
  if (gw >= E) return;
  const int src = ei[gw];
  const int dst = ei[E + gw];
  const uint4 v = *(const uint4*)(h + (size_t)src * HH + lane * 8);
  float* o = agg + (size_t)dst * HH + lane * 8;
  atomicAdd(o + 0, __uint_as_float((v.x & 0xffffu) << 16));
  atomicAdd(o + 1, __uint_as_float(v.x & 0xffff0000u));
  atomicAdd(o + 2, __uint_as_float((v.y & 0xffffu) << 16));
  atomicAdd(o + 3, __uint_as_float(v.y & 0xffff0000u));
  atomicAdd(o + 4, __uint_as_float((v.z & 0xffffu) << 16));
  atomicAdd(o + 5, __uint_as_float(v.z & 0xffff0000u));
  atomicAdd(o + 6, __uint_as_float((v.w & 0xffffu) << 16));
  atomicAdd(o + 7, __uint_as_float(v.w & 0xffff0000u));
}

// ---------------- A1 = bf16((1+eps)*x + agg), F=256 ----------------
__global__ void build_a1(const float* __restrict__ x, const float* __restrict__ agg,
                         const float* __restrict__ eps, ushort* __restrict__ A) {
  const size_t i = ((size_t)blockIdx.x * 256 + threadIdx.x) * 4;
  if (i >= (size_t)NODES * FIN) return;
  const float s = 1.0f + eps[0];
  const float4 xv = *(const float4*)(x + i);
  const float4 av = *(const float4*)(agg + i);
  ushort4 o;
  o.x = f2b(s * xv.x + av.x);
  o.y = f2b(s * xv.y + av.y);
  o.z = f2b(s * xv.z + av.z);
  o.w = f2b(s * xv.w + av.w);
  *(ushort4*)(A + i) = o;
}

// ---------------- A3 = bf16((1+eps)*h_bf16 + agg), F=512 ----------------
__global__ void build_a3(const ushort* __restrict__ h, const float* __restrict__ agg,
                         const float* __restrict__ eps, ushort* __restrict__ A) {
  const size_t i = ((size_t)blockIdx.x * 256 + threadIdx.x) * 8;
  if (i >= (size_t)NODES * HH) return;
  const float s = 1.0f + eps[0];
  const uint4 hv = *(const uint4*)(h + i);
  const float4 a0 = *(const float4*)(agg + i);
  const float4 a1 = *(const float4*)(agg + i + 4);
  const float r0 = s * __uint_as_float((hv.x & 0xffffu) << 16) + a0.x;
  const float r1 = s * __uint_as_float(hv.x & 0xffff0000u) + a0.y;
  const float r2 = s * __uint_as_float((hv.y & 0xffffu) << 16) + a0.z;
  const float r3 = s * __uint_as_float(hv.y & 0xffff0000u) + a0.w;
  const float r4 = s * __uint_as_float((hv.z & 0xffffu) << 16) + a1.x;
  const float r5 = s * __uint_as_float(hv.z & 0xffff0000u) + a1.y;
  const float r6 = s * __uint_as_float((hv.w & 0xffffu) << 16) + a1.z;
  const float r7 = s * __uint_as_float(hv.w & 0xffff0000u) + a1.w;
  uint4 o;
  o.x = (uint)f2b(r0) | ((uint)f2b(r1) << 16);
  o.y = (uint)f2b(r2) | ((uint)f2b(r3) << 16);
  o.z = (uint)f2b(r4) | ((uint)f2b(r5) << 16);
  o.w = (uint)f2b(r6) | ((uint)f2b(r7) << 16);
  *(uint4*)(A + i) = o;
}

// ---------------- column sums / sumsq over Z[M,512] ----------------
__global__ void colstats(const float* __restrict__ Z, float* __restrict__ st, int M) {
  const int t = threadIdx.x;  // 256
  const int r0 = blockIdx.x * 25;
  const int r1 = min(M, r0 + 25);
  float s0 = 0.f, s1 = 0.f, q0 = 0.f, q1 = 0.f;
  for (int r = r0; r < r1; ++r) {
    const float a = Z[(size_t)r * HH + t];
    const float b = Z[(size_t)r * HH + t + 256];
    s0 += a; q0 += a * a;
    s1 += b; q1 += b * b;
  }
  atomicAdd(&st[t], s0);
  atomicAdd(&st[t + 256], s1);
  atomicAdd(&st[HH + t], q0);
  atomicAdd(&st[HH + t + 256], q1);
}

__global__ void bn_finalize(float* __restrict__ st, int M) {
  const int c = threadIdx.x;  // 512
  const float inv = 1.0f / (float)M;
  const float mu = st[c] * inv;
  const float var = st[HH + c] * inv - mu * mu;
  st[c] = mu;
  st[HH + c] = rsqrtf(var + 1e-5f);
}

// ---------------- A = bf16(relu(g*(Z-mu)*rstd + be)) ----------------
__global__ void build_bn(const float* __restrict__ Z, const float* __restrict__ st,
                         const float* __restrict__ g, const float* __restrict__ be,
                         ushort* __restrict__ A, int M) {
  const size_t i = ((size_t)blockIdx.x * 256 + threadIdx.x) * 4;
  if (i >= (size_t)M * HH) return;
  const int c = (int)(i & (HH - 1));
  const float4 z = *(const float4*)(Z + i);
  ushort4 o;
  {
    float v0 = g[c + 0] * (z.x - st[c + 0]) * st[HH + c + 0] + be[c + 0];
    float v1 = g[c + 1] * (z.y - st[c + 1]) * st[HH + c + 1] + be[c + 1];
    float v2 = g[c + 2] * (z.z - st[c + 2]) * st[HH + c + 2] + be[c + 2];
    float v3 = g[c + 3] * (z.w - st[c + 3]) * st[HH + c + 3] + be[c + 3];
    o.x = f2b(fmaxf(v0, 0.f));
    o.y = f2b(fmaxf(v1, 0.f));
    o.z = f2b(fmaxf(v2, 0.f));
    o.w = f2b(fmaxf(v3, 0.f));
  }
  *(ushort4*)(A + i) = o;
}

// ---------------- GEMM: C[M,512] = A[M,K]bf16 * Bt[512,K]bf16^T + bias ----------------
// m97 structure: 128x128 tile, BK=32, 4 waves (2x2), global_load_lds staging,
// XOR swizzle: phys 16B chunk = logical chunk ^ ((row>>1)&3)  (pre-swizzled source,
// swizzled ds_read -> <=2-way bank conflict).
// EPI: 0 = +bias, f32 out; 1 = relu(+bias), bf16 out; 2 = relu(+bias), f32 out.
template <int K, int EPI>
__global__ __launch_bounds__(256)
void gemm_bt(const ushort* __restrict__ A, const ushort* __restrict__ Bt,
             const float* __restrict__ bias, void* __restrict__ Cout, int M) {
  __shared__ ushort lA[128 * 32];
  __shared__ ushort lB[128 * 32];
  const int t = threadIdx.x;
  const int lane = t & 63;
  const int w = t >> 6;
  const int wr = w >> 1, wc = w & 1;
  const int fr = lane & 15, kg = lane >> 4;
  const int rowBase = blockIdx.x * 128;
  const int colBase = blockIdx.y * 128;

  // staging: thread t owns physical 16B slots p0=t, p1=256+t (linear LDS dest)
  const int p0 = t, p1 = 256 + t;
  const int sr0 = p0 >> 2, sc0 = (p0 & 3) ^ ((sr0 >> 1) & 3);
  const int sr1 = p1 >> 2, sc1 = (p1 & 3) ^ ((sr1 >> 1) & 3);
  const int ar0 = min(rowBase + sr0, M - 1);
  const int ar1 = min(rowBase + sr1, M - 1);
  const ushort* gA0 = A + (size_t)ar0 * K + sc0 * 8;
  const ushort* gA1 = A + (size_t)ar1 * K + sc1 * 8;
  const ushort* gB0 = Bt + (size_t)(colBase + sr0) * K + sc0 * 8;
  const ushort* gB1 = Bt + (size_t)(colBase + sr1) * K + sc1 * 8;
  ushort* lA0 = lA + p0 * 8;
  ushort* lA1 = lA + p1 * 8;
  ushort* lB0 = lB + p0 * 8;
  ushort* lB1 = lB + p1 * 8;

  // fragment LDS offsets (ushort units), swizzled read
  int aoff[4], boff[4];
#pragma unroll
  for (int m = 0; m < 4; ++m) {
    const int row = wr * 64 + m * 16 + fr;
    aoff[m] = row * 32 + (kg ^ ((row >> 1) & 3)) * 8;
    const int col = wc * 64 + m * 16 + fr;
    boff[m] = col * 32 + (kg ^ ((col >> 1) & 3)) * 8;
  }

  f32x4 acc[4][4] = {};

  for (int kt = 0; kt < K / 32; ++kt) {
    const int ko = kt * 32;
    async16(gA0 + ko, lA0);
    async16(gA1 + ko, lA1);
    async16(gB0 + ko, lB0);
    async16(gB1 + ko, lB1);
    __syncthreads();  // compiler drains vmcnt before s_barrier
    bfx8 a[4], b[4];
#pragma unroll
    for (int m = 0; m < 4; ++m) a[m] = *(const bfx8*)&lA[aoff[m]];
#pragma unroll
    for (int n = 0; n < 4; ++n) b[n] = *(const bfx8*)&lB[boff[n]];
#pragma unroll
    for (int m = 0; m < 4; ++m)
#pragma unroll
      for (int n = 0; n < 4; ++n)
        acc[m][n] = __builtin_amdgcn_mfma_f32_16x16x32_bf16(a[m], b[n], acc[m][n], 0, 0, 0);
    __syncthreads();
  }

  // epilogue: C/D layout col=lane&15, row=(lane>>4)*4+reg (m89-verified)
#pragma unroll
  for (int m = 0; m < 4; ++m) {
#pragma unroll
    for (int j = 0; j < 4; ++j) {
      const int rr = rowBase + wr * 64 + m * 16 + kg * 4 + j;
      if (rr < M) {
#pragma unroll
        for (int n = 0; n < 4; ++n) {
          const int cc = colBase + wc * 64 + n * 16 + fr;
          float v = acc[m][n][j] + bias[cc];
          if (EPI >= 1) v = fmaxf(v, 0.0f);
          if (EPI == 1)
            ((ushort*)Cout)[(size_t)rr * HH + cc] = f2b(v);
          else
            ((float*)Cout)[(size_t)rr * HH + cc] = v;
        }
      }
    }
  }
}

extern "C" void kernel_launch(void* const* d_in, const int* in_sizes, int n_in,
                              void* d_out, int out_size, void* d_ws, size_t ws_size,
                              hipStream_t stream) {
  const float* x    = (const float*)d_in[0];
  const int*   ei   = (const int*)d_in[1];
  const float* eps1 = (const float*)d_in[2];
  const float* W1   = (const float*)d_in[3];
  const float* b1   = (const float*)d_in[4];
  const float* g1   = (const float*)d_in[5];
  const float* be1  = (const float*)d_in[6];
  const float* W2   = (const float*)d_in[7];
  const float* b2   = (const float*)d_in[8];
  const float* eps2 = (const float*)d_in[9];
  const float* W3   = (const float*)d_in[10];
  const float* b3   = (const float*)d_in[11];
  const float* g2   = (const float*)d_in[12];
  const float* be2  = (const float*)d_in[13];
  const float* W4   = (const float*)d_in[14];
  const float* b4   = (const float*)d_in[15];
  const int E = in_sizes[1] / 2;

  char* ws = (char*)d_ws;
  size_t off = 0;
  auto alloc = [&](size_t bytes) -> char* {
    char* p = ws + off;
    off += (bytes + 255) & ~(size_t)255;
    return p;
  };
  ushort* Wt1 = (ushort*)alloc((size_t)FIN * HH * 2);
  ushort* Wt2 = (ushort*)alloc((size_t)HH * HH * 2);
  ushort* Wt3 = (ushort*)alloc((size_t)HH * HH * 2);
  ushort* Wt4 = (ushort*)alloc((size_t)HH * HH * 2);
  float*  st  = (float*)alloc(2 * HH * 4);
  float*  agg = (float*)alloc((size_t)NODES * HH * 4);   // agg1 (256 cols) / agg2 (512)
  ushort* Abuf= (ushort*)alloc((size_t)NODES * HH * 2);  // A1/A2/A3/A4 (disjoint lifetimes)
  float*  Z   = (float*)alloc((size_t)NODES * HH * 4);   // Z1 / Z2
  ushort* H1  = (ushort*)alloc((size_t)NODES * HH * 2);  // layer-1 output, bf16

  const dim3 gemmGrid((NODES + 127) / 128, HH / 128);

  // weights -> bf16 transposed [N,K]
  wtrans<<<(FIN * HH + 255) / 256, 256, 0, stream>>>(W1, Wt1, FIN, HH);
  wtrans<<<(HH * HH + 255) / 256, 256, 0, stream>>>(W2, Wt2, HH, HH);
  wtrans<<<(HH * HH + 255) / 256, 256, 0, stream>>>(W3, Wt3, HH, HH);
  wtrans<<<(HH * HH + 255) / 256, 256, 0, stream>>>(W4, Wt4, HH, HH);

  // ---- layer 1 ----
  hipMemsetAsync(agg, 0, (size_t)NODES * FIN * 4, stream);
  scatter_f32<<<(E + 3) / 4, 256, 0, stream>>>(x, ei, agg, E);
  build_a1<<<(NODES * FIN / 4 + 255) / 256, 256, 0, stream>>>(x, agg, eps1, Abuf);
  gemm_bt<FIN, 0><<<gemmGrid, 256, 0, stream>>>(Abuf, Wt1, b1, Z, NODES);
  hipMemsetAsync(st, 0, 2 * HH * 4, stream);
  colstats<<<(NODES + 24) / 25, 256, 0, stream>>>(Z, st, NODES);
  bn_finalize<<<1, HH, 0, stream>>>(st, NODES);
  build_bn<<<((size_t)NODES * HH / 4 + 255) / 256, 256, 0, stream>>>(Z, st, g1, be1, Abuf, NODES);
  gemm_bt<HH, 1><<<gemmGrid, 256, 0, stream>>>(Abuf, Wt2, b2, H1, NODES);

  // ---- layer 2 ----
  hipMemsetAsync(agg, 0, (size_t)NODES * HH * 4, stream);
  scatter_bf16<<<(E + 3) / 4, 256, 0, stream>>>(H1, ei, agg, E);
  build_a3<<<((size_t)NODES * HH / 8 + 255) / 256, 256, 0, stream>>>(H1, agg, eps2, Abuf);
  gemm_bt<HH, 0><<<gemmGrid, 256, 0, stream>>>(Abuf, Wt3, b3, Z, NODES);
  hipMemsetAsync(st, 0, 2 * HH * 4, stream);
  colstats<<<(NODES + 24) / 25, 256, 0, stream>>>(Z, st, NODES);
  bn_finalize<<<1, HH, 0, stream>>>(st, NODES);
  build_bn<<<((size_t)NODES * HH / 4 + 255) / 256, 256, 0, stream>>>(Z, st, g2, be2, Abuf, NODES);
  gemm_bt<HH, 2><<<gemmGrid, 256, 0, stream>>>(Abuf, Wt4, b4, (float*)d_out, NODES);
}

// Round 2
// 339.779 us; speedup vs baseline: 16.5399x; 16.5399x over previous
//
#include <hip/hip_runtime.h>
#include <hip/hip_bf16.h>

#define DEVI __device__ __forceinline__

typedef float f32x4 __attribute__((ext_vector_type(4)));
typedef __bf16 bfx8 __attribute__((ext_vector_type(8)));

constexpr int NODES = 20000;
constexpr int FIN = 256;
constexpr int HH = 512;

DEVI ushort f2b(float f) {
  uint x = __float_as_uint(f);
  return (ushort)((x + 0x7fffu + ((x >> 16) & 1u)) >> 16);
}

DEVI void async16(const void* g, void* l) {
  __builtin_amdgcn_global_load_lds(
      (const __attribute__((address_space(1))) void*)g,
      (__attribute__((address_space(3))) void*)l, 16, 0, 0);
}

// ---------------- weight transpose: W[K,N] f32 -> Wt[N,K] bf16 ----------------
__global__ void wtrans(const float* __restrict__ W, ushort* __restrict__ Wt,
                       int K, int N) {
  const int idx = blockIdx.x * 256 + threadIdx.x;
  if (idx >= K * N) return;
  const int n = idx / K;
  const int k = idx - n * K;
  Wt[idx] = f2b(W[(size_t)k * N + n]);
}

// ---------------- CSR build ----------------
__global__ void edge_hist(const int* __restrict__ ei, int* __restrict__ deg, int E) {
  const int e = blockIdx.x * 256 + threadIdx.x;
  if (e < E) atomicAdd(&deg[ei[E + e]], 1);  // dst
}

__global__ void ex_scan(const int* __restrict__ deg, int* __restrict__ off, int n) {
  __shared__ int ps[1024];
  const int t = threadIdx.x;
  const int chunk = (n + 1023) >> 10;
  const int s = t * chunk;
  const int e = min(n, s + chunk);
  int sum = 0;
  for (int i = s; i < e; ++i) sum += deg[i];
  ps[t] = sum;
  __syncthreads();
  for (int d = 1; d < 1024; d <<= 1) {
    int v = (t >= d) ? ps[t - d] : 0;
    __syncthreads();
    ps[t] += v;
    __syncthreads();
  }
  int run = (t == 0) ? 0 : ps[t - 1];
  for (int i = s; i < e; ++i) { off[i] = run; run += deg[i]; }
  if (t == 1023) off[n] = ps[1023];
}

__global__ void edge_fill(const int* __restrict__ ei, const int* __restrict__ off,
                          int* __restrict__ cur, int* __restrict__ csr, int E) {
  const int e = blockIdx.x * 256 + threadIdx.x;
  if (e < E) {
    const int dst = ei[E + e];
    const int p = atomicAdd(&cur[dst], 1);
    csr[off[dst] + p] = ei[e];
  }
}

// ---------------- fused aggregate + (1+eps)x + bf16, layer-1 (f32 in, F=256) ----------------
__global__ void agg_a1(const float* __restrict__ x, const int* __restrict__ off,
                       const int* __restrict__ csr, const float* __restrict__ eps,
                       ushort* __restrict__ A) {
  const int node = (int)((blockIdx.x * 256 + threadIdx.x) >> 6);
  const int lane = threadIdx.x & 63;
  if (node >= NODES) return;
  const float s = 1.0f + eps[0];
  const int b = off[node], e = off[node + 1];
  float4 a0 = {0, 0, 0, 0}, a1 = {0, 0, 0, 0};
  int i = b;
  for (; i + 1 < e; i += 2) {
    const int s0 = csr[i], s1 = csr[i + 1];
    const float4 v0 = *(const float4*)(x + (size_t)s0 * FIN + lane * 4);
    const float4 v1 = *(const float4*)(x + (size_t)s1 * FIN + lane * 4);
    a0.x += v0.x; a0.y += v0.y; a0.z += v0.z; a0.w += v0.w;
    a1.x += v1.x; a1.y += v1.y; a1.z += v1.z; a1.w += v1.w;
  }
  if (i < e) {
    const float4 v0 = *(const float4*)(x + (size_t)csr[i] * FIN + lane * 4);
    a0.x += v0.x; a0.y += v0.y; a0.z += v0.z; a0.w += v0.w;
  }
  const float4 xv = *(const float4*)(x + (size_t)node * FIN + lane * 4);
  ushort4 o;
  o.x = f2b(s * xv.x + a0.x + a1.x);
  o.y = f2b(s * xv.y + a0.y + a1.y);
  o.z = f2b(s * xv.z + a0.z + a1.z);
  o.w = f2b(s * xv.w + a0.w + a1.w);
  *(ushort4*)(A + (size_t)node * FIN + lane * 4) = o;
}

// ---------------- fused aggregate + (1+eps)h + bf16, layer-2 (bf16 in, H=512) ----------------
DEVI void unpack_add(uint4 v, float* a) {
  a[0] += __uint_as_float((v.x & 0xffffu) << 16);
  a[1] += __uint_as_float(v.x & 0xffff0000u);
  a[2] += __uint_as_float((v.y & 0xffffu) << 16);
  a[3] += __uint_as_float(v.y & 0xffff0000u);
  a[4] += __uint_as_float((v.z & 0xffffu) << 16);
  a[5] += __uint_as_float(v.z & 0xffff0000u);
  a[6] += __uint_as_float((v.w & 0xffffu) << 16);
  a[7] += __uint_as_float(v.w & 0xffff0000u);
}

__global__ void agg_a3(const ushort* __restrict__ h, const int* __restrict__ off,
                       const int* __restrict__ csr, const float* __restrict__ eps,
                       ushort* __restrict__ A) {
  const int node = (int)((blockIdx.x * 256 + threadIdx.x) >> 6);
  const int lane = threadIdx.x & 63;
  if (node >= NODES) return;
  const float s = 1.0f + eps[0];
  const int b = off[node], e = off[node + 1];
  float a0[8] = {}, a1[8] = {};
  int i = b;
  for (; i + 1 < e; i += 2) {
    const int s0 = csr[i], s1 = csr[i + 1];
    const uint4 v0 = *(const uint4*)(h + (size_t)s0 * HH + lane * 8);
    const uint4 v1 = *(const uint4*)(h + (size_t)s1 * HH + lane * 8);
    unpack_add(v0, a0);
    unpack_add(v1, a1);
  }
  if (i < e) {
    const uint4 v0 = *(const uint4*)(h + (size_t)csr[i] * HH + lane * 8);
    unpack_add(v0, a0);
  }
  const uint4 hv = *(const uint4*)(h + (size_t)node * HH + lane * 8);
  float self[8] = {};
  unpack_add(hv, self);
  uint4 o;
  float r[8];
#pragma unroll
  for (int j = 0; j < 8; ++j) r[j] = s * self[j] + a0[j] + a1[j];
  o.x = (uint)f2b(r[0]) | ((uint)f2b(r[1]) << 16);
  o.y = (uint)f2b(r[2]) | ((uint)f2b(r[3]) << 16);
  o.z = (uint)f2b(r[4]) | ((uint)f2b(r[5]) << 16);
  o.w = (uint)f2b(r[6]) | ((uint)f2b(r[7]) << 16);
  *(uint4*)(A + (size_t)node * HH + lane * 8) = o;
}

// ---------------- column sums / sumsq over Z[M,512] ----------------
__global__ void colstats(const float* __restrict__ Z, float* __restrict__ st, int M) {
  const int t = threadIdx.x;  // 256
  const int r0 = blockIdx.x * 25;
  const int r1 = min(M, r0 + 25);
  float s0 = 0.f, s1 = 0.f, q0 = 0.f, q1 = 0.f;
  for (int r = r0; r < r1; ++r) {
    const float a = Z[(size_t)r * HH + t];
    const float b = Z[(size_t)r * HH + t + 256];
    s0 += a; q0 += a * a;
    s1 += b; q1 += b * b;
  }
  atomicAdd(&st[t], s0);
  atomicAdd(&st[t + 256], s1);
  atomicAdd(&st[HH + t], q0);
  atomicAdd(&st[HH + t + 256], q1);
}

__global__ void bn_finalize(float* __restrict__ st, int M) {
  const int c = threadIdx.x;  // 512
  const float inv = 1.0f / (float)M;
  const float mu = st[c] * inv;
  const float var = st[HH + c] * inv - mu * mu;
  st[c] = mu;
  st[HH + c] = rsqrtf(var + 1e-5f);
}

// ---------------- A = bf16(relu(g*(Z-mu)*rstd + be)) ----------------
__global__ void build_bn(const float* __restrict__ Z, const float* __restrict__ st,
                         const float* __restrict__ g, const float* __restrict__ be,
                         ushort* __restrict__ A, int M) {
  const size_t i = ((size_t)blockIdx.x * 256 + threadIdx.x) * 4;
  if (i >= (size_t)M * HH) return;
  const int c = (int)(i & (HH - 1));
  const float4 z = *(const float4*)(Z + i);
  ushort4 o;
  {
    float v0 = g[c + 0] * (z.x - st[c + 0]) * st[HH + c + 0] + be[c + 0];
    float v1 = g[c + 1] * (z.y - st[c + 1]) * st[HH + c + 1] + be[c + 1];
    float v2 = g[c + 2] * (z.z - st[c + 2]) * st[HH + c + 2] + be[c + 2];
    float v3 = g[c + 3] * (z.w - st[c + 3]) * st[HH + c + 3] + be[c + 3];
    o.x = f2b(fmaxf(v0, 0.f));
    o.y = f2b(fmaxf(v1, 0.f));
    o.z = f2b(fmaxf(v2, 0.f));
    o.w = f2b(fmaxf(v3, 0.f));
  }
  *(ushort4*)(A + i) = o;
}

// ---------------- GEMM: C[M,512] = A[M,K]bf16 * Bt[512,K]bf16^T + bias ----------------
// m97 structure: 128x128 tile, BK=32, 4 waves (2x2), global_load_lds staging,
// XOR swizzle: phys 16B chunk = logical chunk ^ ((row>>1)&3).
// EPI: 0 = +bias, f32 out; 1 = relu(+bias), bf16 out; 2 = relu(+bias), f32 out.
template <int K, int EPI>
__global__ __launch_bounds__(256)
void gemm_bt(const ushort* __restrict__ A, const ushort* __restrict__ Bt,
             const float* __restrict__ bias, void* __restrict__ Cout, int M) {
  __shared__ ushort lA[128 * 32];
  __shared__ ushort lB[128 * 32];
  const int t = threadIdx.x;
  const int lane = t & 63;
  const int w = t >> 6;
  const int wr = w >> 1, wc = w & 1;
  const int fr = lane & 15, kg = lane >> 4;
  const int rowBase = blockIdx.x * 128;
  const int colBase = blockIdx.y * 128;

  const int p0 = t, p1 = 256 + t;
  const int sr0 = p0 >> 2, sc0 = (p0 & 3) ^ ((sr0 >> 1) & 3);
  const int sr1 = p1 >> 2, sc1 = (p1 & 3) ^ ((sr1 >> 1) & 3);
  const int ar0 = min(rowBase + sr0, M - 1);
  const int ar1 = min(rowBase + sr1, M - 1);
  const ushort* gA0 = A + (size_t)ar0 * K + sc0 * 8;
  const ushort* gA1 = A + (size_t)ar1 * K + sc1 * 8;
  const ushort* gB0 = Bt + (size_t)(colBase + sr0) * K + sc0 * 8;
  const ushort* gB1 = Bt + (size_t)(colBase + sr1) * K + sc1 * 8;
  ushort* lA0 = lA + p0 * 8;
  ushort* lA1 = lA + p1 * 8;
  ushort* lB0 = lB + p0 * 8;
  ushort* lB1 = lB + p1 * 8;

  int aoff[4], boff[4];
#pragma unroll
  for (int m = 0; m < 4; ++m) {
    const int row = wr * 64 + m * 16 + fr;
    aoff[m] = row * 32 + (kg ^ ((row >> 1) & 3)) * 8;
    const int col = wc * 64 + m * 16 + fr;
    boff[m] = col * 32 + (kg ^ ((col >> 1) & 3)) * 8;
  }

  f32x4 acc[4][4] = {};

  for (int kt = 0; kt < K / 32; ++kt) {
    const int ko = kt * 32;
    async16(gA0 + ko, lA0);
    async16(gA1 + ko, lA1);
    async16(gB0 + ko, lB0);
    async16(gB1 + ko, lB1);
    __syncthreads();
    bfx8 a[4], b[4];
#pragma unroll
    for (int m = 0; m < 4; ++m) a[m] = *(const bfx8*)&lA[aoff[m]];
#pragma unroll
    for (int n = 0; n < 4; ++n) b[n] = *(const bfx8*)&lB[boff[n]];
#pragma unroll
    for (int m = 0; m < 4; ++m)
#pragma unroll
      for (int n = 0; n < 4; ++n)
        acc[m][n] = __builtin_amdgcn_mfma_f32_16x16x32_bf16(a[m], b[n], acc[m][n], 0, 0, 0);
    __syncthreads();
  }

#pragma unroll
  for (int m = 0; m < 4; ++m) {
#pragma unroll
    for (int j = 0; j < 4; ++j) {
      const int rr = rowBase + wr * 64 + m * 16 + kg * 4 + j;
      if (rr < M) {
#pragma unroll
        for (int n = 0; n < 4; ++n) {
          const int cc = colBase + wc * 64 + n * 16 + fr;
          float v = acc[m][n][j] + bias[cc];
          if (EPI >= 1) v = fmaxf(v, 0.0f);
          if (EPI == 1)
            ((ushort*)Cout)[(size_t)rr * HH + cc] = f2b(v);
          else
            ((float*)Cout)[(size_t)rr * HH + cc] = v;
        }
      }
    }
  }
}

extern "C" void kernel_launch(void* const* d_in, const int* in_sizes, int n_in,
                              void* d_out, int out_size, void* d_ws, size_t ws_size,
                              hipStream_t stream) {
  const float* x    = (const float*)d_in[0];
  const int*   ei   = (const int*)d_in[1];
  const float* eps1 = (const float*)d_in[2];
  const float* W1   = (const float*)d_in[3];
  const float* b1   = (const float*)d_in[4];
  const float* g1   = (const float*)d_in[5];
  const float* be1  = (const float*)d_in[6];
  const float* W2   = (const float*)d_in[7];
  const float* b2   = (const float*)d_in[8];
  const float* eps2 = (const float*)d_in[9];
  const float* W3   = (const float*)d_in[10];
  const float* b3   = (const float*)d_in[11];
  const float* g2   = (const float*)d_in[12];
  const float* be2  = (const float*)d_in[13];
  const float* W4   = (const float*)d_in[14];
  const float* b4   = (const float*)d_in[15];
  const int E = in_sizes[1] / 2;

  char* ws = (char*)d_ws;
  size_t off = 0;
  auto alloc = [&](size_t bytes) -> char* {
    char* p = ws + off;
    off += (bytes + 255) & ~(size_t)255;
    return p;
  };
  ushort* Wt1 = (ushort*)alloc((size_t)FIN * HH * 2);
  ushort* Wt2 = (ushort*)alloc((size_t)HH * HH * 2);
  ushort* Wt3 = (ushort*)alloc((size_t)HH * HH * 2);
  ushort* Wt4 = (ushort*)alloc((size_t)HH * HH * 2);
  float*  st  = (float*)alloc(2 * HH * 4);
  int*    deg = (int*)alloc((size_t)NODES * 4);
  int*    offs= (int*)alloc(((size_t)NODES + 1) * 4);
  int*    cur = (int*)alloc((size_t)NODES * 4);
  int*    csr = (int*)alloc((size_t)E * 4);
  ushort* Abuf= (ushort*)alloc((size_t)NODES * HH * 2);  // A1/A2/A3/A4 (disjoint lifetimes)
  float*  Z   = (float*)alloc((size_t)NODES * HH * 4);   // Z1 / Z2
  ushort* H1  = (ushort*)alloc((size_t)NODES * HH * 2);  // layer-1 output, bf16

  const dim3 gemmGrid((NODES + 127) / 128, HH / 128);
  const int nodeBlocks = (NODES * 64 + 255) / 256;

  // weights -> bf16 transposed [N,K]
  wtrans<<<(FIN * HH + 255) / 256, 256, 0, stream>>>(W1, Wt1, FIN, HH);
  wtrans<<<(HH * HH + 255) / 256, 256, 0, stream>>>(W2, Wt2, HH, HH);
  wtrans<<<(HH * HH + 255) / 256, 256, 0, stream>>>(W3, Wt3, HH, HH);
  wtrans<<<(HH * HH + 255) / 256, 256, 0, stream>>>(W4, Wt4, HH, HH);

  // CSR build (shared by both layers)
  hipMemsetAsync(deg, 0, (size_t)NODES * 4, stream);
  hipMemsetAsync(cur, 0, (size_t)NODES * 4, stream);
  edge_hist<<<(E + 255) / 256, 256, 0, stream>>>(ei, deg, E);
  ex_scan<<<1, 1024, 0, stream>>>(deg, offs, NODES);
  edge_fill<<<(E + 255) / 256, 256, 0, stream>>>(ei, offs, cur, csr, E);

  // ---- layer 1 ----
  agg_a1<<<nodeBlocks, 256, 0, stream>>>(x, offs, csr, eps1, Abuf);
  gemm_bt<FIN, 0><<<gemmGrid, 256, 0, stream>>>(Abuf, Wt1, b1, Z, NODES);
  hipMemsetAsync(st, 0, 2 * HH * 4, stream);
  colstats<<<(NODES + 24) / 25, 256, 0, stream>>>(Z, st, NODES);
  bn_finalize<<<1, HH, 0, stream>>>(st, NODES);
  build_bn<<<((size_t)NODES * HH / 4 + 255) / 256, 256, 0, stream>>>(Z, st, g1, be1, Abuf, NODES);
  gemm_bt<HH, 1><<<gemmGrid, 256, 0, stream>>>(Abuf, Wt2, b2, H1, NODES);

  // ---- layer 2 ----
  agg_a3<<<nodeBlocks, 256, 0, stream>>>(H1, offs, csr, eps2, Abuf);
  gemm_bt<HH, 0><<<gemmGrid, 256, 0, stream>>>(Abuf, Wt3, b3, Z, NODES);
  hipMemsetAsync(st, 0, 2 * HH * 4, stream);
  colstats<<<(NODES + 24) / 25, 256, 0, stream>>>(Z, st, NODES);
  bn_finalize<<<1, HH, 0, stream>>>(st, NODES);
  build_bn<<<((size_t)NODES * HH / 4 + 255) / 256, 256, 0, stream>>>(Z, st, g2, be2, Abuf, NODES);
  gemm_bt<HH, 2><<<gemmGrid, 256, 0, stream>>>(Abuf, Wt4, b4, (float*)d_out, NODES);
}

// Round 3
// 247.279 us; speedup vs baseline: 22.7270x; 1.3741x over previous
//
#include <hip/hip_runtime.h>
#include <hip/hip_bf16.h>

#define DEVI __device__ __forceinline__

typedef float f32x4 __attribute__((ext_vector_type(4)));
typedef __bf16 bfx8 __attribute__((ext_vector_type(8)));

constexpr int NODES = 20000;
constexpr int FIN = 256;
constexpr int HH = 512;

DEVI ushort f2b(float f) {
  uint x = __float_as_uint(f);
  return (ushort)((x + 0x7fffu + ((x >> 16) & 1u)) >> 16);
}

DEVI void async16(const void* g, void* l) {
  __builtin_amdgcn_global_load_lds(
      (const __attribute__((address_space(1))) void*)g,
      (__attribute__((address_space(3))) void*)l, 16, 0, 0);
}

// ---------------- prep: 4x weight transpose (LDS-tiled) + x->bf16 ----------------
// blocks 0..895: 32x32 transpose tiles (W1:128, W2/3/4: 256 each)
// blocks 896+:   x -> bf16 elementwise (1024 elems/block)
__global__ __launch_bounds__(256)
void prep(const float* __restrict__ W1, const float* __restrict__ W2,
          const float* __restrict__ W3, const float* __restrict__ W4,
          const float* __restrict__ x,
          ushort* __restrict__ Wt1, ushort* __restrict__ Wt2,
          ushort* __restrict__ Wt3, ushort* __restrict__ Wt4,
          ushort* __restrict__ xb) {
  const int b = blockIdx.x, t = threadIdx.x;
  if (b < 896) {
    __shared__ float tile[32][33];
    const float* W;
    ushort* Wt;
    int K, N, tk, tn;
    if (b < 128) {
      W = W1; Wt = Wt1; K = FIN; N = HH; tk = b & 7; tn = b >> 3;
    } else if (b < 384) {
      W = W2; Wt = Wt2; K = HH; N = HH; const int bb = b - 128; tk = bb & 15; tn = bb >> 4;
    } else if (b < 640) {
      W = W3; Wt = Wt3; K = HH; N = HH; const int bb = b - 384; tk = bb & 15; tn = bb >> 4;
    } else {
      W = W4; Wt = Wt4; K = HH; N = HH; const int bb = b - 640; tk = bb & 15; tn = bb >> 4;
    }
    const int k0 = tk * 32, n0 = tn * 32;
    const int r = t >> 5, c = t & 31;
#pragma unroll
    for (int rr = r; rr < 32; rr += 8)
      tile[rr][c] = W[(size_t)(k0 + rr) * N + n0 + c];
    __syncthreads();
#pragma unroll
    for (int rr = r; rr < 32; rr += 8)
      Wt[(size_t)(n0 + rr) * K + k0 + c] = f2b(tile[c][rr]);
  } else {
    const size_t i = ((size_t)(b - 896) * 256 + t) * 4;
    if (i < (size_t)NODES * FIN) {
      const float4 v = *(const float4*)(x + i);
      ushort4 o;
      o.x = f2b(v.x); o.y = f2b(v.y); o.z = f2b(v.z); o.w = f2b(v.w);
      *(ushort4*)(xb + i) = o;
    }
  }
}

// ---------------- CSR build ----------------
__global__ void edge_hist(const int* __restrict__ ei, int* __restrict__ deg, int E) {
  const int e = blockIdx.x * 256 + threadIdx.x;
  if (e < E) atomicAdd(&deg[ei[E + e]], 1);  // dst
}

__global__ void ex_scan(const int* __restrict__ deg, int* __restrict__ off, int n) {
  __shared__ int ps[1024];
  const int t = threadIdx.x;
  const int chunk = (n + 1023) >> 10;
  const int s = t * chunk;
  const int e = min(n, s + chunk);
  int sum = 0;
  for (int i = s; i < e; ++i) sum += deg[i];
  ps[t] = sum;
  __syncthreads();
  for (int d = 1; d < 1024; d <<= 1) {
    int v = (t >= d) ? ps[t - d] : 0;
    __syncthreads();
    ps[t] += v;
    __syncthreads();
  }
  int run = (t == 0) ? 0 : ps[t - 1];
  for (int i = s; i < e; ++i) { off[i] = run; run += deg[i]; }
  if (t == 1023) off[n] = ps[1023];
}

__global__ void edge_fill(const int* __restrict__ ei, const int* __restrict__ off,
                          int* __restrict__ cur, int* __restrict__ csr, int E) {
  const int e = blockIdx.x * 256 + threadIdx.x;
  if (e < E) {
    const int dst = ei[E + e];
    const int p = atomicAdd(&cur[dst], 1);
    csr[off[dst] + p] = ei[e];
  }
}

// ---------------- XCD-sliced fused aggregate: A = bf16((1+eps)*h + sum_src h) ----------------
// 8-lane group per node per 64-col slice; slice = blockIdx % NSLICE -> pins the
// 2.5MB gather slice to one XCD's L2 (round-robin block->XCD dispatch heuristic).
DEVI void unpack_add(uint4 v, float* a) {
  a[0] += __uint_as_float((v.x & 0xffffu) << 16);
  a[1] += __uint_as_float(v.x & 0xffff0000u);
  a[2] += __uint_as_float((v.y & 0xffffu) << 16);
  a[3] += __uint_as_float(v.y & 0xffff0000u);
  a[4] += __uint_as_float((v.z & 0xffffu) << 16);
  a[5] += __uint_as_float(v.z & 0xffff0000u);
  a[6] += __uint_as_float((v.w & 0xffffu) << 16);
  a[7] += __uint_as_float(v.w & 0xffff0000u);
}

template <int C>  // C = 256 (NS=4) or 512 (NS=8)
__global__ __launch_bounds__(256)
void agg_gin(const ushort* __restrict__ h, const int* __restrict__ off,
             const int* __restrict__ csr, const float* __restrict__ eps,
             ushort* __restrict__ A) {
  constexpr int NS = C / 64;
  const int slice = blockIdx.x & (NS - 1);
  const int chunk = blockIdx.x / NS;
  const int node = chunk * 32 + (threadIdx.x >> 3);
  if (node >= NODES) return;
  const int l = threadIdx.x & 7;
  const int col = slice * 64 + l * 8;  // ushort units; 16B per lane
  const ushort* base = h + col;
  const float s = 1.0f + eps[0];
  const int b = off[node], e = off[node + 1];
  float a0[8] = {}, a1[8] = {};
  int i = b;
  for (; i + 1 < e; i += 2) {
    const uint4 v0 = *(const uint4*)(base + (size_t)csr[i] * C);
    const uint4 v1 = *(const uint4*)(base + (size_t)csr[i + 1] * C);
    unpack_add(v0, a0);
    unpack_add(v1, a1);
  }
  if (i < e) {
    const uint4 v0 = *(const uint4*)(base + (size_t)csr[i] * C);
    unpack_add(v0, a0);
  }
  const uint4 hv = *(const uint4*)(base + (size_t)node * C);
  float self[8] = {};
  unpack_add(hv, self);
  float r[8];
#pragma unroll
  for (int j = 0; j < 8; ++j) r[j] = s * self[j] + a0[j] + a1[j];
  uint4 o;
  o.x = (uint)f2b(r[0]) | ((uint)f2b(r[1]) << 16);
  o.y = (uint)f2b(r[2]) | ((uint)f2b(r[3]) << 16);
  o.z = (uint)f2b(r[4]) | ((uint)f2b(r[5]) << 16);
  o.w = (uint)f2b(r[6]) | ((uint)f2b(r[7]) << 16);
  *(uint4*)(A + (size_t)node * C + col) = o;
}

// ---------------- BN normalize (stats computed inline from raw sums) + ReLU + bf16 ----------------
__global__ void build_bn(const float* __restrict__ Z, const float* __restrict__ st,
                         const float* __restrict__ g, const float* __restrict__ be,
                         ushort* __restrict__ A, int M) {
  const size_t i = ((size_t)blockIdx.x * 256 + threadIdx.x) * 4;
  if (i >= (size_t)M * HH) return;
  const int c = (int)(i & (HH - 1));
  const float inv = 1.0f / (float)M;
  const float4 z = *(const float4*)(Z + i);
  ushort4 o;
  {
    float v[4] = {z.x, z.y, z.z, z.w};
    ushort ov[4];
#pragma unroll
    for (int k = 0; k < 4; ++k) {
      const float mu = st[c + k] * inv;
      const float var = st[HH + c + k] * inv - mu * mu;
      const float rs = rsqrtf(var + 1e-5f);
      const float y = g[c + k] * (v[k] - mu) * rs + be[c + k];
      ov[k] = f2b(fmaxf(y, 0.f));
    }
    o.x = ov[0]; o.y = ov[1]; o.z = ov[2]; o.w = ov[3];
  }
  *(ushort4*)(A + i) = o;
}

// ---------------- GEMM: C[M,512] = A[M,K]bf16 * Bt[512,K]bf16^T + bias ----------------
// m97 structure: 128x128 tile, BK=32, 4 waves (2x2), global_load_lds staging,
// XOR swizzle: phys 16B chunk = logical chunk ^ ((row>>1)&3).
// EPI: 0 = +bias f32 out; 1 = relu bf16 out; 2 = relu f32 out.
// STATS: fused column sum/sumsq atomics into st[0..511]=sum, st[512..1023]=sumsq.
template <int K, int EPI, bool STATS>
__global__ __launch_bounds__(256)
void gemm_bt(const ushort* __restrict__ A, const ushort* __restrict__ Bt,
             const float* __restrict__ bias, void* __restrict__ Cout,
             float* __restrict__ st, int M) {
  __shared__ ushort lA[128 * 32];
  __shared__ ushort lB[128 * 32];
  const int t = threadIdx.x;
  const int lane = t & 63;
  const int w = t >> 6;
  const int wr = w >> 1, wc = w & 1;
  const int fr = lane & 15, kg = lane >> 4;
  const int rowBase = blockIdx.x * 128;
  const int colBase = blockIdx.y * 128;

  const int p0 = t, p1 = 256 + t;
  const int sr0 = p0 >> 2, sc0 = (p0 & 3) ^ ((sr0 >> 1) & 3);
  const int sr1 = p1 >> 2, sc1 = (p1 & 3) ^ ((sr1 >> 1) & 3);
  const int ar0 = min(rowBase + sr0, M - 1);
  const int ar1 = min(rowBase + sr1, M - 1);
  const ushort* gA0 = A + (size_t)ar0 * K + sc0 * 8;
  const ushort* gA1 = A + (size_t)ar1 * K + sc1 * 8;
  const ushort* gB0 = Bt + (size_t)(colBase + sr0) * K + sc0 * 8;
  const ushort* gB1 = Bt + (size_t)(colBase + sr1) * K + sc1 * 8;
  ushort* lA0 = lA + p0 * 8;
  ushort* lA1 = lA + p1 * 8;
  ushort* lB0 = lB + p0 * 8;
  ushort* lB1 = lB + p1 * 8;

  int aoff[4], boff[4];
#pragma unroll
  for (int m = 0; m < 4; ++m) {
    const int row = wr * 64 + m * 16 + fr;
    aoff[m] = row * 32 + (kg ^ ((row >> 1) & 3)) * 8;
    const int col = wc * 64 + m * 16 + fr;
    boff[m] = col * 32 + (kg ^ ((col >> 1) & 3)) * 8;
  }

  f32x4 acc[4][4] = {};

  for (int kt = 0; kt < K / 32; ++kt) {
    const int ko = kt * 32;
    async16(gA0 + ko, lA0);
    async16(gA1 + ko, lA1);
    async16(gB0 + ko, lB0);
    async16(gB1 + ko, lB1);
    __syncthreads();
    bfx8 a[4], b[4];
#pragma unroll
    for (int m = 0; m < 4; ++m) a[m] = *(const bfx8*)&lA[aoff[m]];
#pragma unroll
    for (int n = 0; n < 4; ++n) b[n] = *(const bfx8*)&lB[boff[n]];
#pragma unroll
    for (int m = 0; m < 4; ++m)
#pragma unroll
      for (int n = 0; n < 4; ++n)
        acc[m][n] = __builtin_amdgcn_mfma_f32_16x16x32_bf16(a[m], b[n], acc[m][n], 0, 0, 0);
    __syncthreads();
  }

  float sc_[4] = {}, qc_[4] = {};
#pragma unroll
  for (int m = 0; m < 4; ++m) {
#pragma unroll
    for (int j = 0; j < 4; ++j) {
      const int rr = rowBase + wr * 64 + m * 16 + kg * 4 + j;
      if (rr < M) {
#pragma unroll
        for (int n = 0; n < 4; ++n) {
          const int cc = colBase + wc * 64 + n * 16 + fr;
          float v = acc[m][n][j] + bias[cc];
          if (STATS) { sc_[n] += v; qc_[n] += v * v; }
          if (EPI >= 1) v = fmaxf(v, 0.0f);
          if (EPI == 1)
            ((ushort*)Cout)[(size_t)rr * HH + cc] = f2b(v);
          else
            ((float*)Cout)[(size_t)rr * HH + cc] = v;
        }
      }
    }
  }
  if (STATS) {
#pragma unroll
    for (int n = 0; n < 4; ++n) {
      float s = sc_[n], q = qc_[n];
      s += __shfl_xor(s, 16, 64); q += __shfl_xor(q, 16, 64);
      s += __shfl_xor(s, 32, 64); q += __shfl_xor(q, 32, 64);
      if (kg == 0) {
        const int cc = colBase + wc * 64 + n * 16 + fr;
        atomicAdd(&st[cc], s);
        atomicAdd(&st[HH + cc], q);
      }
    }
  }
}

extern "C" void kernel_launch(void* const* d_in, const int* in_sizes, int n_in,
                              void* d_out, int out_size, void* d_ws, size_t ws_size,
                              hipStream_t stream) {
  const float* x    = (const float*)d_in[0];
  const int*   ei   = (const int*)d_in[1];
  const float* eps1 = (const float*)d_in[2];
  const float* W1   = (const float*)d_in[3];
  const float* b1   = (const float*)d_in[4];
  const float* g1   = (const float*)d_in[5];
  const float* be1  = (const float*)d_in[6];
  const float* W2   = (const float*)d_in[7];
  const float* b2   = (const float*)d_in[8];
  const float* eps2 = (const float*)d_in[9];
  const float* W3   = (const float*)d_in[10];
  const float* b3   = (const float*)d_in[11];
  const float* g2   = (const float*)d_in[12];
  const float* be2  = (const float*)d_in[13];
  const float* W4   = (const float*)d_in[14];
  const float* b4   = (const float*)d_in[15];
  const int E = in_sizes[1] / 2;

  char* ws = (char*)d_ws;
  size_t off = 0;
  auto alloc = [&](size_t bytes) -> char* {
    char* p = ws + off;
    off += (bytes + 255) & ~(size_t)255;
    return p;
  };
  // zero-region: deg, cur, st1, st2 (one memset)
  const size_t ZB = 2 * (size_t)NODES * 4 + 4 * HH * 4;
  char* zb    = alloc(ZB);
  int* deg    = (int*)zb;
  int* cur    = deg + NODES;
  float* st1  = (float*)(cur + NODES);
  float* st2  = st1 + 2 * HH;
  int*    offs= (int*)alloc(((size_t)NODES + 1) * 4);
  int*    csr = (int*)alloc((size_t)E * 4);
  ushort* Wt1 = (ushort*)alloc((size_t)FIN * HH * 2);
  ushort* Wt2 = (ushort*)alloc((size_t)HH * HH * 2);
  ushort* Wt3 = (ushort*)alloc((size_t)HH * HH * 2);
  ushort* Wt4 = (ushort*)alloc((size_t)HH * HH * 2);
  ushort* xb  = (ushort*)alloc((size_t)NODES * FIN * 2);
  ushort* Abuf= (ushort*)alloc((size_t)NODES * HH * 2);  // A1/A2/A3/A4 (disjoint lifetimes)
  float*  Z   = (float*)alloc((size_t)NODES * HH * 4);   // Z1 / Z2
  ushort* H1  = (ushort*)alloc((size_t)NODES * HH * 2);  // layer-1 output, bf16

  const dim3 gemmGrid((NODES + 127) / 128, HH / 128);

  hipMemsetAsync(zb, 0, ZB, stream);
  prep<<<896 + (NODES * FIN / 1024), 256, 0, stream>>>(W1, W2, W3, W4, x,
                                                       Wt1, Wt2, Wt3, Wt4, xb);
  edge_hist<<<(E + 255) / 256, 256, 0, stream>>>(ei, deg, E);
  ex_scan<<<1, 1024, 0, stream>>>(deg, offs, NODES);
  edge_fill<<<(E + 255) / 256, 256, 0, stream>>>(ei, offs, cur, csr, E);

  // ---- layer 1 ----
  agg_gin<FIN><<<(NODES / 32) * 4, 256, 0, stream>>>(xb, offs, csr, eps1, Abuf);
  gemm_bt<FIN, 0, true><<<gemmGrid, 256, 0, stream>>>(Abuf, Wt1, b1, Z, st1, NODES);
  build_bn<<<(NODES * HH / 4) / 256, 256, 0, stream>>>(Z, st1, g1, be1, Abuf, NODES);
  gemm_bt<HH, 1, false><<<gemmGrid, 256, 0, stream>>>(Abuf, Wt2, b2, H1, nullptr, NODES);

  // ---- layer 2 ----
  agg_gin<HH><<<(NODES / 32) * 8, 256, 0, stream>>>(H1, offs, csr, eps2, Abuf);
  gemm_bt<HH, 0, true><<<gemmGrid, 256, 0, stream>>>(Abuf, Wt3, b3, Z, st2, NODES);
  build_bn<<<(NODES * HH / 4) / 256, 256, 0, stream>>>(Z, st2, g2, be2, Abuf, NODES);
  gemm_bt<HH, 2, false><<<gemmGrid, 256, 0, stream>>>(Abuf, Wt4, b4, (float*)d_out, nullptr, NODES);
}